// Round 12
// baseline (192.230 us; speedup 1.0000x reference)
//
#include <hip/hip_runtime.h>
#include <hip/hip_bf16.h>
#include <math.h>

// Problem: B=2, S=2048, D=1024, H=16, dk=64. fp32 in/out, bf16 MFMA compute.
#define NUM_HEADS 16
#define DK 64
#define SEQ 2048
#define BATCHN 2
#define DM 1024
#define BS (BATCHN*SEQ)          // 4096
#define LSCALE 0.18033688011112042f   // 0.125 * log2(e), folded into Q

typedef __bf16 bf16x8 __attribute__((ext_vector_type(8)));
typedef float floatx4 __attribute__((ext_vector_type(4)));
typedef unsigned short ushort;
typedef unsigned int uint;

__device__ __forceinline__ ushort f2bu(float f){
    union { __hip_bfloat16 h; ushort u; } cv; cv.h = __float2bfloat16(f); return cv.u;
}
__device__ __forceinline__ uint packbf(float a, float b){
    return (uint)f2bu(a) | ((uint)f2bu(b) << 16);
}
__device__ __forceinline__ float bu2f(ushort u){
    union { uint u; float f; } cv; cv.u = (uint)u << 16; return cv.f;
}
// single-inst packed f32x2 -> bf16x2 (RNE); no builtin on gfx950 (T12 recipe)
__device__ __forceinline__ uint cvtpk(float lo, float hi){
    uint r; asm("v_cvt_pk_bf16_f32 %0, %1, %2" : "=v"(r) : "v"(lo), "v"(hi));
    return r;
}
// async global->LDS, 16 B per lane; LDS dst must be wave-uniform-base + lane*16
__device__ __forceinline__ void gl16(const void* g, void* l){
    __builtin_amdgcn_global_load_lds(
        (const __attribute__((address_space(1))) unsigned int*)g,
        (__attribute__((address_space(3))) unsigned int*)l, 16, 0, 0);
}

// ---------------------------------------------------------------------------
// Fused fp32->bf16 casts + RoPE table (one launch, 4352 blocks).
// ---------------------------------------------------------------------------
__global__ __launch_bounds__(256)
void castall(const float* __restrict__ x,  const float* __restrict__ wq,
             const float* __restrict__ wk, const float* __restrict__ wv,
             const float* __restrict__ wo, const int* __restrict__ pos,
             ushort* __restrict__ xb, ushort* __restrict__ wqkb,
             ushort* __restrict__ wvb, ushort* __restrict__ wob,
             float2* __restrict__ tab)
{
    int bid = blockIdx.x;
    if (bid >= 4096) {
        int idx = (bid - 4096)*256 + threadIdx.x;   // 0..65535
        int s = idx >> 5, i = idx & 31;
        float invf = expf(-0.28782313662425575f * (float)i);  // ln(1e4)/32
        float ang = (float)pos[s] * invf;
        float sn, cs; sincosf(ang, &sn, &cs);
        tab[idx] = make_float2(cs, sn);
        return;
    }
    const float* src; ushort* dst; int off;
    if (bid < 2048)      { src = x;  dst = xb;             off = bid; }
    else if (bid < 2560) { src = wq; dst = wqkb;           off = bid - 2048; }
    else if (bid < 3072) { src = wk; dst = wqkb + 1048576; off = bid - 2560; }
    else if (bid < 3584) { src = wv; dst = wvb;            off = bid - 3072; }
    else                 { src = wo; dst = wob;            off = bid - 3584; }
    int i = off*2048 + threadIdx.x*8;
    float4 a = *(const float4*)(src+i);
    float4 b = *(const float4*)(src+i+4);
    uint4 o;
    o.x = packbf(a.x, a.y);
    o.y = packbf(a.z, a.w);
    o.z = packbf(b.x, b.y);
    o.w = packbf(b.z, b.w);
    *(uint4*)(dst+i) = o;
}

// ---------------------------------------------------------------------------
// Fused projections, 128x128 tiles (768 blocks).
// R12 change (isolated, proj only): T3+T4 minimum 2-phase (m248v2-verified):
// BK=32 double-buffer (32 KB, same 3 blocks/CU), ONE barrier per K-step:
//   prologue: STAGE(buf0,k=0); vmcnt(0); bar;
//   loop:     STAGE(buf^1, k+32);          // DMA issued BEFORE compute
//             ds_read+MFMA(buf);           // ~800cy covers DMA latency
//             vmcnt(0); bar; buf ^= 1;     // drains loads issued 800cy ago
// Differs from failed R4/R5: one barrier (not two), stage-before-compute.
// Race-free: the single barrier jointly orders {DMA(t+1) done} and
// {all ds_reads of the to-be-overwritten buffer done}.
// R0 bank-uniform [.][32] layout. XCD 2D-region swizzle kept (R9).
//   work 0..511  : QK proj + RoPE scatter [b,h,s,64]; Q scaled by LSCALE.
//   work 512..767: V^T proj row-major [1024, 4096].
// ---------------------------------------------------------------------------
__global__ __launch_bounds__(256)
void proj_fused(const ushort* __restrict__ xb, const ushort* __restrict__ Wqkb,
                const ushort* __restrict__ Wvb, ushort* __restrict__ Qb,
                ushort* __restrict__ VTp, const float2* __restrict__ rope)
{
    __shared__ ushort As[2*128*32];   // 2 x 8 KB
    __shared__ ushort Bs[2*128*32];   // 2 x 8 KB

    const int bx = blockIdx.x;
    int bid;
    if (bx < 512) {
        const int xcd = bx & 7, i = bx >> 3;       // i: 0..63
        const int tr = (xcd >> 1)*8 + (i >> 3);    // 0..31
        const int tc = (xcd & 1)*8 + (i & 7);      // 0..15
        bid = tr*16 + tc;
    } else {
        const int j = bx - 512;
        const int xcd = j & 7, i = j >> 3;         // i: 0..31
        const int tr = i >> 2;                     // 0..7
        const int tc = xcd*4 + (i & 3);            // 0..31
        bid = 512 + tr*32 + tc;
    }

    const ushort* A; const ushort* W; int row0, col0, mode;
    if (bid < 512) { A = xb;  W = Wqkb; row0 = (bid >> 4) * 128;
                     col0 = (bid & 15) * 128;  mode = 1; }
    else           { int i = bid - 512; A = Wvb; W = xb;
                     row0 = (i >> 5) * 128; col0 = (i & 31) * 128; mode = 2; }

    const int t = threadIdx.x;
    const int w = t >> 6;
    const int L = t & 63;
    const int lr = L & 15;
    const int lq = L >> 4;
    const int wrow = w * 32;

    floatx4 acc[2][8];
    #pragma unroll
    for (int i = 0; i < 2; ++i)
        #pragma unroll
        for (int j = 0; j < 8; ++j)
            acc[i][j] = (floatx4){0.f,0.f,0.f,0.f};

    const int rr = t >> 2, ko = (t & 3) * 8;   // LDS offset = t*16 B (lane-contig)
    const ushort* ga = A + (size_t)(row0 + rr) * DM + ko;
    const ushort* gb = W + (size_t)(col0 + rr) * DM + ko;
    const int ldst = rr*32 + ko;               // = t*16 bytes within a buffer

#define STG(BUF, K0)                                                          \
    {                                                                         \
        gl16(ga + (K0),                 &As[(BUF)*4096 + ldst]);              \
        gl16(ga + (K0) + (size_t)64*DM, &As[(BUF)*4096 + 2048 + ldst]);       \
        gl16(gb + (K0),                 &Bs[(BUF)*4096 + ldst]);              \
        gl16(gb + (K0) + (size_t)64*DM, &Bs[(BUF)*4096 + 2048 + ldst]);       \
    }

    STG(0, 0)
    asm volatile("s_waitcnt vmcnt(0)" ::: "memory");
    __builtin_amdgcn_s_barrier();

    int cur = 0;
    for (int k0 = 0; k0 < DM; k0 += 32) {
        // stage NEXT tile first — its latency hides under this tile's compute
        if (k0 + 32 < DM) STG(cur ^ 1, k0 + 32)

        const ushort* Ac = As + cur*4096;
        const ushort* Bc = Bs + cur*4096;
        bf16x8 aF0 = *(const bf16x8*)&Ac[(wrow + lr)*32 + lq*8];
        bf16x8 aF1 = *(const bf16x8*)&Ac[(wrow + 16 + lr)*32 + lq*8];
        #pragma unroll
        for (int tc = 0; tc < 8; ++tc) {
            bf16x8 bF = *(const bf16x8*)&Bc[(tc*16 + lr)*32 + lq*8];
            acc[0][tc] = __builtin_amdgcn_mfma_f32_16x16x32_bf16(aF0, bF, acc[0][tc], 0, 0, 0);
            acc[1][tc] = __builtin_amdgcn_mfma_f32_16x16x32_bf16(aF1, bF, acc[1][tc], 0, 0, 0);
        }
        // one barrier per K-step: orders DMA(t+1) completion AND protects the
        // buffer we overwrite next iteration from in-flight ds_reads.
        asm volatile("s_waitcnt vmcnt(0) lgkmcnt(0)" ::: "memory");
        __builtin_amdgcn_s_barrier();
        cur ^= 1;
    }
#undef STG

    // C layout: col = col0 + tc*16 + lr, row = row0+wrow+tr*16+lq*4+r
    if (mode == 2) {
        #pragma unroll
        for (int tr = 0; tr < 2; ++tr)
            #pragma unroll
            for (int tc = 0; tc < 8; ++tc)
                #pragma unroll
                for (int r = 0; r < 4; ++r) {
                    int m = row0 + wrow + tr*16 + lq*4 + r;
                    int c = col0 + tc*16 + lr;
                    VTp[(size_t)m * BS + c] = f2bu(acc[tr][tc][r]);
                }
    } else {
        const int mat = col0 >> 10;             // 0 = Q, 1 = K (tile never straddles)
        const int base_hh = (col0 & 1023) >> 6;
        ushort* out = Qb + (size_t)mat * (BATCHN*NUM_HEADS*SEQ*DK);
        const float qscale = mat ? 1.f : LSCALE;
        #pragma unroll
        for (int tr = 0; tr < 2; ++tr)
            #pragma unroll
            for (int tc = 0; tc < 8; ++tc)
                #pragma unroll
                for (int r = 0; r < 4; ++r) {
                    int m = row0 + wrow + tr*16 + lq*4 + r;
                    int b = m >> 11;
                    int s = m & (SEQ - 1);
                    int dd = (tc*16 + lr) & 63;
                    int hh = base_hh + (tc >> 2);
                    float v = acc[tr][tc][r];
                    float o = __shfl_xor(v, 1, 64);
                    float2 cs = rope[s*32 + (dd >> 1)];
                    float rv = (dd & 1) ? fmaf(o, cs.y,  v * cs.x)
                                        : fmaf(-o, cs.y, v * cs.x);
                    out[((size_t)((b*NUM_HEADS + hh)*SEQ + s))*DK + dd] =
                        f2bu(rv * qscale);
                }
    }
}

// ---------------------------------------------------------------------------
// Out projection, 128x64 tiles (512 blocks), BK=64 (16 iterations) — R11
// state, measured fine. LDS 24KB; grid-limited at 2 blocks/CU.
// out[m,n] = sum_k attnb[m,k]*Wo[n,k], fp32.  grid (16, 32).
// ---------------------------------------------------------------------------
__global__ __launch_bounds__(256)
void gemm_out(const ushort* __restrict__ A, const ushort* __restrict__ W,
              float* __restrict__ out)
{
    __shared__ ushort As[128*64];   // 16 KB
    __shared__ ushort Bs[64*64];    //  8 KB

    const int t = threadIdx.x;
    const int w = t >> 6;
    const int L = t & 63;
    const int lr = L & 15;
    const int lq = L >> 4;
    const int row0 = blockIdx.y * 128;
    const int col0 = blockIdx.x * 64;
    const int wrow = w * 32;

    floatx4 acc[2][4];
    #pragma unroll
    for (int i = 0; i < 2; ++i)
        #pragma unroll
        for (int j = 0; j < 4; ++j)
            acc[i][j] = (floatx4){0.f,0.f,0.f,0.f};

    const int rr = t >> 3;
    const int ko = ((t & 7) ^ (rr & 7)) * 8;
    const ushort* ga = A + (size_t)(row0 + rr) * DM + ko;
    const ushort* gb = W + (size_t)(col0 + rr) * DM + ko;
    ushort* Asl = As + t*8;
    ushort* Bsl = Bs + t*8;

    for (int k0 = 0; k0 < DM; k0 += 64) {
        __syncthreads();
        gl16(ga + k0,                 Asl);
        gl16(ga + k0 + (size_t)32*DM, Asl + 2048);
        gl16(ga + k0 + (size_t)64*DM, Asl + 4096);
        gl16(ga + k0 + (size_t)96*DM, Asl + 6144);
        gl16(gb + k0,                 Bsl);
        gl16(gb + k0 + (size_t)32*DM, Bsl + 2048);
        __syncthreads();

        #pragma unroll
        for (int h = 0; h < 2; ++h) {
            const int co = (lq*8 + h*32) ^ ((lr & 7) << 3);
            bf16x8 aF0 = *(const bf16x8*)&As[(wrow + lr)*64 + co];
            bf16x8 aF1 = *(const bf16x8*)&As[(wrow + 16 + lr)*64 + co];
            #pragma unroll
            for (int tc = 0; tc < 4; ++tc) {
                bf16x8 bF = *(const bf16x8*)&Bs[(tc*16 + lr)*64 + co];
                acc[0][tc] = __builtin_amdgcn_mfma_f32_16x16x32_bf16(aF0, bF, acc[0][tc], 0, 0, 0);
                acc[1][tc] = __builtin_amdgcn_mfma_f32_16x16x32_bf16(aF1, bF, acc[1][tc], 0, 0, 0);
            }
        }
    }

    #pragma unroll
    for (int tr = 0; tr < 2; ++tr)
        #pragma unroll
        for (int tc = 0; tc < 4; ++tc)
            #pragma unroll
            for (int r = 0; r < 4; ++r) {
                int m = row0 + wrow + tr*16 + lq*4 + r;
                int c = col0 + tc*16 + lr;
                out[(size_t)m * DM + c] = acc[tr][tc][r];
            }
}

// ---------------------------------------------------------------------------
// Flash attention, bf16 MFMA, no-max softmax, transposed QK (S^T = K·Q^T).
// 2 waves x 32 q-rows each (128 threads). Key-permuted V layout makes each
// lane's packed QK^T outputs directly the PV A-fragment (no P LDS round-trip).
// Ks/Vs XOR-swizzled (idx ^= (row&7)<<3) -> bank-uniform (verified: 0 confl).
// VALU-thin hot loop: raw v_exp_f32, v_cvt_pk_bf16_f32, mask hoisted to the
// (single) last tile, row-sum l via MFMA against an all-ones B fragment.
// T14: next-tile K/V prefetched into regs; latency hides under compute.
// ---------------------------------------------------------------------------
__global__ __launch_bounds__(128)
void attn_mfma(const ushort* __restrict__ Qb, const ushort* __restrict__ Kb,
               const ushort* __restrict__ VT, ushort* __restrict__ attnb,
               ushort* __restrict__ Opart, float* __restrict__ lpart)
{
    __shared__ ushort Ks[64*64];      // [key][dim], swizzled
    __shared__ ushort Vs[64*64];      // [dim][pos], pos-permuted + swizzled

    const int t = threadIdx.x;
    const int w = t >> 6;
    const int L = t & 63;
    const int lr = L & 15, lq = L >> 4;
    const int h  = blockIdx.y;
    const int b  = blockIdx.z;

    // chunk mapping: bx 0..79
    int qt, chunk, nch;
    {
        const int bx = blockIdx.x;
        if (bx < 8)       { qt = bx;              chunk = 0;     nch = 1; }
        else if (bx < 24) { int i = bx - 8;  qt = 8  + (i>>1); chunk = i&1;        nch = 2; }
        else if (bx < 48) { int i = bx - 24; int q3 = i/3; qt = 16 + q3; chunk = i - q3*3; nch = 3; }
        else              { int i = bx - 48; qt = 24 + (i>>2); chunk = i&3;        nch = 4; }
    }
    const int nt = qt + 1;
    const int t0 = (nt * chunk) / nch;
    const int t1 = (nt * (chunk + 1)) / nch;
    const int q0 = qt * 64;
    const int qw = q0 + w * 32;
    const size_t qkbase = (size_t)(b*NUM_HEADS + h) * SEQ * DK;

    bf16x8 qA0, qA1, qB0, qB1;
    {
        const ushort* qp = Qb + qkbase + (size_t)(qw + lr) * DK + lq*8;
        qA0 = *(const bf16x8*)qp;
        qA1 = *(const bf16x8*)(qp + 32);
        qB0 = *(const bf16x8*)(qp + 16*DK);
        qB1 = *(const bf16x8*)(qp + 16*DK + 32);
    }

    bf16x8 ones8;
    {
        union { uint u[4]; bf16x8 v; } o;
        o.u[0] = o.u[1] = o.u[2] = o.u[3] = 0x3f803f80u;   // bf16 1.0 x2
        ones8 = o.v;
    }

    floatx4 O0[4], O1[4];
    #pragma unroll
    for (int g = 0; g < 4; ++g) {
        O0[g] = (floatx4){0.f,0.f,0.f,0.f};
        O1[g] = (floatx4){0.f,0.f,0.f,0.f};
    }
    floatx4 lA = (floatx4){0.f,0.f,0.f,0.f};
    floatx4 lB = (floatx4){0.f,0.f,0.f,0.f};

    // staging geometry: 128 threads, 8/row; 4 row-passes (sr+16j) per matrix
    const int sr = t >> 3, t7 = t & 7;
    const int kwb  = (sr*64 + t7*8) ^ ((sr & 7) << 3);
    // V key-chunk kc=2*t7 -> pos-chunk pc0 = 8*(kc>>3)+2*(kc&3)+((kc>>2)&1)
    const int pc0  = ((t7 >> 2) << 3) | ((t7 & 1) << 2) | ((t7 >> 1) & 1);
    const int vwb0 = (sr*64 + pc0*4)     ^ ((sr & 7) << 3);
    const int vwb1 = (sr*64 + pc0*4 + 8) ^ ((sr & 7) << 3);
    const ushort* kpt = Kb + qkbase + (size_t)sr * DK + t7*8;
    const ushort* vpt = VT + ((size_t)(h*DK + sr)) * BS + b*SEQ + t7*8;

    // fragment read offsets (tile-invariant; +g*1024 folds into ds offset imm)
    const int kro0 = (lr*64 + lq*8)      ^ ((lr & 7) << 3);
    const int kro1 = (lr*64 + 32 + lq*8) ^ ((lr & 7) << 3);

    uint4 kv0, kv1, kv2, kv3, vv0, vv1, vv2, vv3;

#define GLOAD(T)                                                              \
    {                                                                         \
        const ushort* kg = kpt + (size_t)(T) * 64 * DK;                       \
        const ushort* vg = vpt + (T) * 64;                                    \
        kv0 = *(const uint4*)(kg);                                            \
        kv1 = *(const uint4*)(kg + 16*DK);                                    \
        kv2 = *(const uint4*)(kg + 32*DK);                                    \
        kv3 = *(const uint4*)(kg + 48*DK);                                    \
        vv0 = *(const uint4*)(vg);                                            \
        vv1 = *(const uint4*)(vg + (size_t)16*BS);                            \
        vv2 = *(const uint4*)(vg + (size_t)32*BS);                            \
        vv3 = *(const uint4*)(vg + (size_t)48*BS);                            \
    }

#define STAGE()                                                               \
    {                                                                         \
        *(uint4*)&Ks[kwb]        = kv0;                                       \
        *(uint4*)&Ks[kwb + 1024] = kv1;                                       \
        *(uint4*)&Ks[kwb + 2048] = kv2;                                       \
        *(uint4*)&Ks[kwb + 3072] = kv3;                                       \
        *(uint2*)&Vs[vwb0]        = make_uint2(vv0.x, vv0.y);                 \
        *(uint2*)&Vs[vwb1]        = make_uint2(vv0.z, vv0.w);                 \
        *(uint2*)&Vs[vwb0 + 1024] = make_uint2(vv1.x, vv1.y);                 \
        *(uint2*)&Vs[vwb1 + 1024] = make_uint2(vv1.z, vv1.w);                 \
        *(uint2*)&Vs[vwb0 + 2048] = make_uint2(vv2.x, vv2.y);                 \
        *(uint2*)&Vs[vwb1 + 2048] = make_uint2(vv2.z, vv2.w);                 \
        *(uint2*)&Vs[vwb0 + 3072] = make_uint2(vv3.x, vv3.y);                 \
        *(uint2*)&Vs[vwb1 + 3072] = make_uint2(vv3.z, vv3.w);                 \
    }

#define COMPUTE(LASTT)                                                        \
    {                                                                         \
        uint2 pk0[4], pk1[4];                                                 \
        _Pragma("unroll")                                                     \
        for (int g = 0; g < 4; ++g) {                                         \
            bf16x8 kf0 = *(const bf16x8*)&Ks[kro0 + g*1024];                  \
            bf16x8 kf1 = *(const bf16x8*)&Ks[kro1 + g*1024];                  \
            floatx4 s0 = (floatx4){0.f,0.f,0.f,0.f};                          \
            s0 = __builtin_amdgcn_mfma_f32_16x16x32_bf16(kf0, qA0, s0,0,0,0); \
            s0 = __builtin_amdgcn_mfma_f32_16x16x32_bf16(kf1, qA1, s0,0,0,0); \
            floatx4 s1 = (floatx4){0.f,0.f,0.f,0.f};                          \
            s1 = __builtin_amdgcn_mfma_f32_16x16x32_bf16(kf0, qB0, s1,0,0,0); \
            s1 = __builtin_amdgcn_mfma_f32_16x16x32_bf16(kf1, qB1, s1,0,0,0); \
            float a0 = __builtin_amdgcn_exp2f(s0[0]);                         \
            float a1 = __builtin_amdgcn_exp2f(s0[1]);                         \
            float a2 = __builtin_amdgcn_exp2f(s0[2]);                         \
            float a3 = __builtin_amdgcn_exp2f(s0[3]);                         \
            float b0 = __builtin_amdgcn_exp2f(s1[0]);                         \
            float b1 = __builtin_amdgcn_exp2f(s1[1]);                         \
            float b2 = __builtin_amdgcn_exp2f(s1[2]);                         \
            float b3 = __builtin_amdgcn_exp2f(s1[3]);                         \
            if (LASTT) {                                                      \
                const int kbase = g*16 + lq*4;                                \
                a0 = (kbase + 0 <= lim0) ? a0 : 0.f;                          \
                a1 = (kbase + 1 <= lim0) ? a1 : 0.f;                          \
                a2 = (kbase + 2 <= lim0) ? a2 : 0.f;                          \
                a3 = (kbase + 3 <= lim0) ? a3 : 0.f;                          \
                b0 = (kbase + 0 <= lim1) ? b0 : 0.f;                          \
                b1 = (kbase + 1 <= lim1) ? b1 : 0.f;                          \
                b2 = (kbase + 2 <= lim1) ? b2 : 0.f;                          \
                b3 = (kbase + 3 <= lim1) ? b3 : 0.f;                          \
            }                                                                 \
            pk0[g] = make_uint2(cvtpk(a0, a1), cvtpk(a2, a3));                \
            pk1[g] = make_uint2(cvtpk(b0, b1), cvtpk(b2, b3));                \
        }                                                                     \
        _Pragma("unroll")                                                     \
        for (int c = 0; c < 2; ++c) {                                         \
            union { uint u[4]; bf16x8 v; } a0u, a1u;                          \
            a0u.u[0] = pk0[2*c].x;   a0u.u[1] = pk0[2*c].y;                   \
            a0u.u[2] = pk0[2*c+1].x; a0u.u[3] = pk0[2*c+1].y;                 \
            a1u.u[0] = pk1[2*c].x;   a1u.u[1] = pk1[2*c].y;                   \
            a1u.u[2] = pk1[2*c+1].x; a1u.u[3] = pk1[2*c+1].y;                 \
            lA = __builtin_amdgcn_mfma_f32_16x16x32_bf16(a0u.v, ones8, lA,0,0,0); \
            lB = __builtin_amdgcn_mfma_f32_16x16x32_bf16(a1u.v, ones8, lB,0,0,0); \
            const int vro = c ? kro1 : kro0;                                  \
            _Pragma("unroll")                                                 \
            for (int g2 = 0; g2 < 4; ++g2) {                                  \
                bf16x8 vf = *(const bf16x8*)&Vs[vro + g2*1024];               \
                O0[g2] = __builtin_amdgcn_mfma_f32_16x16x32_bf16(a0u.v, vf, O0[g2],0,0,0); \
                O1[g2] = __builtin_amdgcn_mfma_f32_16x16x32_bf16(a1u.v, vf, O1[g2],0,0,0); \
            }                                                                 \
        }                                                                     \
    }

    GLOAD(t0);
    const bool haslast = (t1 == nt);          // this chunk owns the masked tile
    const int tmain = haslast ? t1 - 1 : t1;
    {
        const int lim0 = 0, lim1 = 0;          // unused (mask folded away)
        for (int tile = t0; tile < tmain; ++tile) {
            __syncthreads();
            STAGE();
            __syncthreads();
            if (tile + 1 < t1) GLOAD(tile + 1);
            COMPUTE(false);
        }
    }
    if (haslast) {
        __syncthreads();
        STAGE();
        __syncthreads();
        const int lim0 = qw + lr - (nt - 1)*64;
        const int lim1 = lim0 + 16;
        COMPUTE(true);
    }
#undef GLOAD
#undef STAGE
#undef COMPUTE

    // lA[r] = sum_k P for q-row lq*4+r (replicated across lr); lB: rows 16-31
    if (nch == 1) {
        #pragma unroll
        for (int r = 0; r < 4; ++r) {
            float li0 = 1.f / lA[r];
            float li1 = 1.f / lB[r];
            int s0r = qw + lq*4 + r;
            int s1r = qw + 16 + lq*4 + r;
            #pragma unroll
            for (int g2 = 0; g2 < 4; ++g2) {
                attnb[((size_t)(b*SEQ + s0r))*DM + h*DK + g2*16 + lr] = f2bu(O0[g2][r] * li0);
                attnb[((size_t)(b*SEQ + s1r))*DM + h*DK + g2*16 + lr] = f2bu(O1[g2][r] * li1);
            }
        }
    } else {
        const int slot = ((b*NUM_HEADS + h)*24 + (qt - 8))*4 + chunk;
        ushort* Op = Opart + (size_t)slot * 4096;
        #pragma unroll
        for (int r = 0; r < 4; ++r) {
            int ql0 = w*32 + lq*4 + r;
            int ql1 = w*32 + 16 + lq*4 + r;
            #pragma unroll
            for (int g2 = 0; g2 < 4; ++g2) {
                Op[ql0*64 + g2*16 + lr] = f2bu(O0[g2][r]);
                Op[ql1*64 + g2*16 + lr] = f2bu(O1[g2][r]);
            }
        }
        if (lr == 0) {
            #pragma unroll
            for (int r = 0; r < 4; ++r) {
                lpart[(size_t)slot*64 + w*32 + lq*4 + r]      = lA[r];
                lpart[(size_t)slot*64 + w*32 + 16 + lq*4 + r] = lB[r];
            }
        }
    }
}

// ---------------------------------------------------------------------------
// Combine: for qt>=8, O = (sum_c O_c)/(sum_c l_c) -> attnb bf16.
// grid 768 = 32 (b,h) x 24 qt.
// ---------------------------------------------------------------------------
__global__ __launch_bounds__(256)
void combine(const ushort* __restrict__ Opart, const float* __restrict__ lpart,
             ushort* __restrict__ attnb)
{
    int gx = blockIdx.x;
    int qti = gx % 24, bh = gx / 24;
    int h = bh & 15, b = bh >> 4;
    int qt = 8 + qti;
    int nch = (qt >> 3) + 1;          // 2..4
    int tid = threadIdx.x;
    int row = tid >> 2, c0 = (tid & 3) * 16;
    const int base_slot = (bh*24 + qti)*4;

    float acc[16];
    #pragma unroll
    for (int e = 0; e < 16; ++e) acc[e] = 0.f;
    float l = 0.f;

    for (int c = 0; c < nch; ++c) {
        const ushort* Op = Opart + (size_t)(base_slot + c)*4096 + row*64 + c0;
        uint4 u0 = *(const uint4*)(Op);
        uint4 u1 = *(const uint4*)(Op + 8);
        const ushort* h0 = (const ushort*)&u0;
        const ushort* h1 = (const ushort*)&u1;
        #pragma unroll
        for (int e = 0; e < 8; ++e) { acc[e]   += bu2f(h0[e]); }
        #pragma unroll
        for (int e = 0; e < 8; ++e) { acc[8+e] += bu2f(h1[e]); }
        l += lpart[(size_t)(base_slot + c)*64 + row];
    }
    float li = 1.f / l;
    int s = qt*64 + row;
    ushort* dst = attnb + ((size_t)(b*SEQ + s))*DM + h*DK + c0;
    #pragma unroll
    for (int e = 0; e < 16; ++e) dst[e] = f2bu(acc[e] * li);
}

// ---------------------------------------------------------------------------
extern "C" void kernel_launch(void* const* d_in, const int* in_sizes, int n_in,
                              void* d_out, int out_size, void* d_ws, size_t ws_size,
                              hipStream_t stream) {
    const float* x   = (const float*)d_in[0];
    const float* Wq  = (const float*)d_in[1];
    const float* Wk  = (const float*)d_in[2];
    const float* Wv  = (const float*)d_in[3];
    const float* Wo  = (const float*)d_in[4];
    const int*   pos = (const int*)d_in[5];
    float* out = (float*)d_out;

    const size_t MB = 1u << 20;
    char* ws = (char*)d_ws;
    // xb/Wqkb/Wvb dead after projections; Opart (24 MB) aliases them.
    ushort* xb    = (ushort*)(ws);             //  8 MB  [4096,1024]
    ushort* Wqkb  = (ushort*)(ws +  8*MB);     //  4 MB  [Wq;Wk]
    ushort* Wvb   = (ushort*)(ws + 12*MB);     //  2 MB
    ushort* Opart = (ushort*)(ws);             // 24 MB  [3072 slots][64][64] bf16
    float*  lpart = (float*)(ws + 24*MB);      //  768 KB
    ushort* Qb    = (ushort*)(ws + 25*MB);     //  8 MB  [b,h,s,64] (Q scaled)
    ushort* Kb    = (ushort*)(ws + 33*MB);     //  8 MB  (== Qb + 4194304)
    ushort* VT    = (ushort*)(ws + 41*MB);     //  8 MB  [h*64+dv, b*2048+s]
    ushort* attnb = (ushort*)(ws + 49*MB);     //  8 MB  [4096,1024]
    float2* ropeT = (float2*)(ws + 57*MB);     //  0.5 MB
    ushort* Wob   = (ushort*)(ws + 58*MB);     //  2 MB  (survives to out-GEMM)

    dim3 blk(256);
    castall<<<4352, blk, 0, stream>>>(x, Wq, Wk, Wv, Wo, pos,
                                      xb, Wqkb, Wvb, Wob, ropeT);

    proj_fused<<<768, blk, 0, stream>>>(xb, Wqkb, Wvb, Qb, VT, ropeT);

    attn_mfma<<<dim3(80, NUM_HEADS, BATCHN), dim3(128), 0, stream>>>(Qb, Kb, VT, attnb,
                                                                     Opart, lpart);
    combine<<<768, blk, 0, stream>>>(Opart, lpart, attnb);

    gemm_out<<<dim3(16,32), blk, 0, stream>>>(attnb, Wob, out);
}

// Round 13
// 187.053 us; speedup vs baseline: 1.0277x; 1.0277x over previous
//
#include <hip/hip_runtime.h>
#include <hip/hip_bf16.h>
#include <math.h>

// Problem: B=2, S=2048, D=1024, H=16, dk=64. fp32 in/out, bf16 MFMA compute.
#define NUM_HEADS 16
#define DK 64
#define SEQ 2048
#define BATCHN 2
#define DM 1024
#define BS (BATCHN*SEQ)          // 4096
#define LSCALE 0.18033688011112042f   // 0.125 * log2(e), folded into Q

typedef __bf16 bf16x8 __attribute__((ext_vector_type(8)));
typedef float floatx4 __attribute__((ext_vector_type(4)));
typedef unsigned short ushort;
typedef unsigned int uint;

__device__ __forceinline__ ushort f2bu(float f){
    union { __hip_bfloat16 h; ushort u; } cv; cv.h = __float2bfloat16(f); return cv.u;
}
__device__ __forceinline__ uint packbf(float a, float b){
    return (uint)f2bu(a) | ((uint)f2bu(b) << 16);
}
__device__ __forceinline__ float bu2f(ushort u){
    union { uint u; float f; } cv; cv.u = (uint)u << 16; return cv.f;
}
// single-inst packed f32x2 -> bf16x2 (RNE); no builtin on gfx950 (T12 recipe)
__device__ __forceinline__ uint cvtpk(float lo, float hi){
    uint r; asm("v_cvt_pk_bf16_f32 %0, %1, %2" : "=v"(r) : "v"(lo), "v"(hi));
    return r;
}
// async global->LDS, 16 B per lane; LDS dst must be wave-uniform-base + lane*16
__device__ __forceinline__ void gl16(const void* g, void* l){
    __builtin_amdgcn_global_load_lds(
        (const __attribute__((address_space(1))) unsigned int*)g,
        (__attribute__((address_space(3))) unsigned int*)l, 16, 0, 0);
}

// ---------------------------------------------------------------------------
// Fused fp32->bf16 casts + RoPE table (one launch, 4352 blocks).
// ---------------------------------------------------------------------------
__global__ __launch_bounds__(256)
void castall(const float* __restrict__ x,  const float* __restrict__ wq,
             const float* __restrict__ wk, const float* __restrict__ wv,
             const float* __restrict__ wo, const int* __restrict__ pos,
             ushort* __restrict__ xb, ushort* __restrict__ wqkb,
             ushort* __restrict__ wvb, ushort* __restrict__ wob,
             float2* __restrict__ tab)
{
    int bid = blockIdx.x;
    if (bid >= 4096) {
        int idx = (bid - 4096)*256 + threadIdx.x;   // 0..65535
        int s = idx >> 5, i = idx & 31;
        float invf = expf(-0.28782313662425575f * (float)i);  // ln(1e4)/32
        float ang = (float)pos[s] * invf;
        float sn, cs; sincosf(ang, &sn, &cs);
        tab[idx] = make_float2(cs, sn);
        return;
    }
    const float* src; ushort* dst; int off;
    if (bid < 2048)      { src = x;  dst = xb;             off = bid; }
    else if (bid < 2560) { src = wq; dst = wqkb;           off = bid - 2048; }
    else if (bid < 3072) { src = wk; dst = wqkb + 1048576; off = bid - 2560; }
    else if (bid < 3584) { src = wv; dst = wvb;            off = bid - 3072; }
    else                 { src = wo; dst = wob;            off = bid - 3584; }
    int i = off*2048 + threadIdx.x*8;
    float4 a = *(const float4*)(src+i);
    float4 b = *(const float4*)(src+i+4);
    uint4 o;
    o.x = packbf(a.x, a.y);
    o.y = packbf(a.z, a.w);
    o.z = packbf(b.x, b.y);
    o.w = packbf(b.z, b.w);
    *(uint4*)(dst+i) = o;
}

// ---------------------------------------------------------------------------
// Fused projections, 128x128 tiles (768 blocks). LOCKED at the measured floor:
// BK=64 (16 iters, 50.9 us R11), R0 2-sync gl16 skeleton, chunk-swizzled
// [128][64] layout (source-permute ko=((t&7)^(rr&7))*8, read col^((lr&7)<<3)),
// XCD 2D-region swizzle (FETCH 49->30 MB, R9).
// Post-R12 note: 8 structural variants measured; dbuf/counted-vmcnt/
// single-barrier-2phase/reg-staged/64^2 all 53-71 us. Do not re-tweak.
//   work 0..511  : QK proj + RoPE scatter [b,h,s,64]; Q scaled by LSCALE.
//   work 512..767: V^T proj row-major [1024, 4096].
// ---------------------------------------------------------------------------
__global__ __launch_bounds__(256)
void proj_fused(const ushort* __restrict__ xb, const ushort* __restrict__ Wqkb,
                const ushort* __restrict__ Wvb, ushort* __restrict__ Qb,
                ushort* __restrict__ VTp, const float2* __restrict__ rope)
{
    __shared__ ushort As[128*64];   // 16 KB, row stride 64 ushort, chunk-swizzled
    __shared__ ushort Bs[128*64];   // 16 KB

    const int bx = blockIdx.x;
    int bid;
    if (bx < 512) {
        const int xcd = bx & 7, i = bx >> 3;       // i: 0..63
        const int tr = (xcd >> 1)*8 + (i >> 3);    // 0..31
        const int tc = (xcd & 1)*8 + (i & 7);      // 0..15
        bid = tr*16 + tc;
    } else {
        const int j = bx - 512;
        const int xcd = j & 7, i = j >> 3;         // i: 0..31
        const int tr = i >> 2;                     // 0..7
        const int tc = xcd*4 + (i & 3);            // 0..31
        bid = 512 + tr*32 + tc;
    }

    const ushort* A; const ushort* W; int row0, col0, mode;
    if (bid < 512) { A = xb;  W = Wqkb; row0 = (bid >> 4) * 128;
                     col0 = (bid & 15) * 128;  mode = 1; }
    else           { int i = bid - 512; A = Wvb; W = xb;
                     row0 = (i >> 5) * 128; col0 = (i & 31) * 128; mode = 2; }

    const int t = threadIdx.x;
    const int w = t >> 6;
    const int L = t & 63;
    const int lr = L & 15;
    const int lq = L >> 4;
    const int wrow = w * 32;

    floatx4 acc[2][8];
    #pragma unroll
    for (int i = 0; i < 2; ++i)
        #pragma unroll
        for (int j = 0; j < 8; ++j)
            acc[i][j] = (floatx4){0.f,0.f,0.f,0.f};

    // staging: 4 row-passes of 32 rows; thread t -> row 32p+(t>>3), chunk t&7.
    // Source chunk permuted so the linear gl16 dest lands swizzled.
    const int rr = t >> 3;
    const int ko = ((t & 7) ^ (rr & 7)) * 8;
    const ushort* ga = A + (size_t)(row0 + rr) * DM + ko;
    const ushort* gb = W + (size_t)(col0 + rr) * DM + ko;
    ushort* Asl = As + t*8;   // byte offset t*16, wave-uniform base + lane*16
    ushort* Bsl = Bs + t*8;

    for (int k0 = 0; k0 < DM; k0 += 64) {
        __syncthreads();
        gl16(ga + k0,                 Asl);
        gl16(ga + k0 + (size_t)32*DM, Asl + 2048);
        gl16(ga + k0 + (size_t)64*DM, Asl + 4096);
        gl16(ga + k0 + (size_t)96*DM, Asl + 6144);
        gl16(gb + k0,                 Bsl);
        gl16(gb + k0 + (size_t)32*DM, Bsl + 2048);
        gl16(gb + k0 + (size_t)64*DM, Bsl + 4096);
        gl16(gb + k0 + (size_t)96*DM, Bsl + 6144);
        __syncthreads();

        #pragma unroll
        for (int h = 0; h < 2; ++h) {
            const int co = (lq*8 + h*32) ^ ((lr & 7) << 3);
            bf16x8 aF0 = *(const bf16x8*)&As[(wrow + lr)*64 + co];
            bf16x8 aF1 = *(const bf16x8*)&As[(wrow + 16 + lr)*64 + co];
            #pragma unroll
            for (int tc = 0; tc < 8; ++tc) {
                bf16x8 bF = *(const bf16x8*)&Bs[(tc*16 + lr)*64 + co];
                acc[0][tc] = __builtin_amdgcn_mfma_f32_16x16x32_bf16(aF0, bF, acc[0][tc], 0, 0, 0);
                acc[1][tc] = __builtin_amdgcn_mfma_f32_16x16x32_bf16(aF1, bF, acc[1][tc], 0, 0, 0);
            }
        }
    }

    // C layout: col = col0 + tc*16 + lr, row = row0+wrow+tr*16+lq*4+r
    if (mode == 2) {
        #pragma unroll
        for (int tr = 0; tr < 2; ++tr)
            #pragma unroll
            for (int tc = 0; tc < 8; ++tc)
                #pragma unroll
                for (int r = 0; r < 4; ++r) {
                    int m = row0 + wrow + tr*16 + lq*4 + r;
                    int c = col0 + tc*16 + lr;
                    VTp[(size_t)m * BS + c] = f2bu(acc[tr][tc][r]);
                }
    } else {
        const int mat = col0 >> 10;             // 0 = Q, 1 = K (tile never straddles)
        const int base_hh = (col0 & 1023) >> 6;
        ushort* out = Qb + (size_t)mat * (BATCHN*NUM_HEADS*SEQ*DK);
        const float qscale = mat ? 1.f : LSCALE;
        #pragma unroll
        for (int tr = 0; tr < 2; ++tr)
            #pragma unroll
            for (int tc = 0; tc < 8; ++tc)
                #pragma unroll
                for (int r = 0; r < 4; ++r) {
                    int m = row0 + wrow + tr*16 + lq*4 + r;
                    int b = m >> 11;
                    int s = m & (SEQ - 1);
                    int dd = (tc*16 + lr) & 63;
                    int hh = base_hh + (tc >> 2);
                    float v = acc[tr][tc][r];
                    float o = __shfl_xor(v, 1, 64);
                    float2 cs = rope[s*32 + (dd >> 1)];
                    float rv = (dd & 1) ? fmaf(o, cs.y,  v * cs.x)
                                        : fmaf(-o, cs.y, v * cs.x);
                    out[((size_t)((b*NUM_HEADS + hh)*SEQ + s))*DK + dd] =
                        f2bu(rv * qscale);
                }
    }
}

// ---------------------------------------------------------------------------
// Out projection, 128x64 tiles (512 blocks), BK=64 (16 iterations) — R11
// state, measured fine. LDS 24KB; grid-limited at 2 blocks/CU.
// out[m,n] = sum_k attnb[m,k]*Wo[n,k], fp32.  grid (16, 32).
// ---------------------------------------------------------------------------
__global__ __launch_bounds__(256)
void gemm_out(const ushort* __restrict__ A, const ushort* __restrict__ W,
              float* __restrict__ out)
{
    __shared__ ushort As[128*64];   // 16 KB
    __shared__ ushort Bs[64*64];    //  8 KB

    const int t = threadIdx.x;
    const int w = t >> 6;
    const int L = t & 63;
    const int lr = L & 15;
    const int lq = L >> 4;
    const int row0 = blockIdx.y * 128;
    const int col0 = blockIdx.x * 64;
    const int wrow = w * 32;

    floatx4 acc[2][4];
    #pragma unroll
    for (int i = 0; i < 2; ++i)
        #pragma unroll
        for (int j = 0; j < 4; ++j)
            acc[i][j] = (floatx4){0.f,0.f,0.f,0.f};

    const int rr = t >> 3;
    const int ko = ((t & 7) ^ (rr & 7)) * 8;
    const ushort* ga = A + (size_t)(row0 + rr) * DM + ko;
    const ushort* gb = W + (size_t)(col0 + rr) * DM + ko;
    ushort* Asl = As + t*8;
    ushort* Bsl = Bs + t*8;

    for (int k0 = 0; k0 < DM; k0 += 64) {
        __syncthreads();
        gl16(ga + k0,                 Asl);
        gl16(ga + k0 + (size_t)32*DM, Asl + 2048);
        gl16(ga + k0 + (size_t)64*DM, Asl + 4096);
        gl16(ga + k0 + (size_t)96*DM, Asl + 6144);
        gl16(gb + k0,                 Bsl);
        gl16(gb + k0 + (size_t)32*DM, Bsl + 2048);
        __syncthreads();

        #pragma unroll
        for (int h = 0; h < 2; ++h) {
            const int co = (lq*8 + h*32) ^ ((lr & 7) << 3);
            bf16x8 aF0 = *(const bf16x8*)&As[(wrow + lr)*64 + co];
            bf16x8 aF1 = *(const bf16x8*)&As[(wrow + 16 + lr)*64 + co];
            #pragma unroll
            for (int tc = 0; tc < 4; ++tc) {
                bf16x8 bF = *(const bf16x8*)&Bs[(tc*16 + lr)*64 + co];
                acc[0][tc] = __builtin_amdgcn_mfma_f32_16x16x32_bf16(aF0, bF, acc[0][tc], 0, 0, 0);
                acc[1][tc] = __builtin_amdgcn_mfma_f32_16x16x32_bf16(aF1, bF, acc[1][tc], 0, 0, 0);
            }
        }
    }

    #pragma unroll
    for (int tr = 0; tr < 2; ++tr)
        #pragma unroll
        for (int tc = 0; tc < 4; ++tc)
            #pragma unroll
            for (int r = 0; r < 4; ++r) {
                int m = row0 + wrow + tr*16 + lq*4 + r;
                int c = col0 + tc*16 + lr;
                out[(size_t)m * DM + c] = acc[tr][tc][r];
            }
}

// ---------------------------------------------------------------------------
// Flash attention, bf16 MFMA, no-max softmax, transposed QK (S^T = K·Q^T).
// 2 waves x 32 q-rows each (128 threads). Key-permuted V layout makes each
// lane's packed QK^T outputs directly the PV A-fragment (no P LDS round-trip).
// Ks/Vs XOR-swizzled (idx ^= (row&7)<<3) -> bank-uniform (verified: 0 confl).
// VALU-thin hot loop: raw v_exp_f32, v_cvt_pk_bf16_f32, mask hoisted to the
// (single) last tile, row-sum l via MFMA against an all-ones B fragment.
// T14: next-tile K/V prefetched into regs; latency hides under compute.
// R13: T5 setprio(1) around the PV MFMA cluster — ~8 independent blocks/CU
// at different phases (m191 regime: attn +4-7%; GEMM lockstep null).
// ---------------------------------------------------------------------------
__global__ __launch_bounds__(128)
void attn_mfma(const ushort* __restrict__ Qb, const ushort* __restrict__ Kb,
               const ushort* __restrict__ VT, ushort* __restrict__ attnb,
               ushort* __restrict__ Opart, float* __restrict__ lpart)
{
    __shared__ ushort Ks[64*64];      // [key][dim], swizzled
    __shared__ ushort Vs[64*64];      // [dim][pos], pos-permuted + swizzled

    const int t = threadIdx.x;
    const int w = t >> 6;
    const int L = t & 63;
    const int lr = L & 15, lq = L >> 4;
    const int h  = blockIdx.y;
    const int b  = blockIdx.z;

    // chunk mapping: bx 0..79
    int qt, chunk, nch;
    {
        const int bx = blockIdx.x;
        if (bx < 8)       { qt = bx;              chunk = 0;     nch = 1; }
        else if (bx < 24) { int i = bx - 8;  qt = 8  + (i>>1); chunk = i&1;        nch = 2; }
        else if (bx < 48) { int i = bx - 24; int q3 = i/3; qt = 16 + q3; chunk = i - q3*3; nch = 3; }
        else              { int i = bx - 48; qt = 24 + (i>>2); chunk = i&3;        nch = 4; }
    }
    const int nt = qt + 1;
    const int t0 = (nt * chunk) / nch;
    const int t1 = (nt * (chunk + 1)) / nch;
    const int q0 = qt * 64;
    const int qw = q0 + w * 32;
    const size_t qkbase = (size_t)(b*NUM_HEADS + h) * SEQ * DK;

    bf16x8 qA0, qA1, qB0, qB1;
    {
        const ushort* qp = Qb + qkbase + (size_t)(qw + lr) * DK + lq*8;
        qA0 = *(const bf16x8*)qp;
        qA1 = *(const bf16x8*)(qp + 32);
        qB0 = *(const bf16x8*)(qp + 16*DK);
        qB1 = *(const bf16x8*)(qp + 16*DK + 32);
    }

    bf16x8 ones8;
    {
        union { uint u[4]; bf16x8 v; } o;
        o.u[0] = o.u[1] = o.u[2] = o.u[3] = 0x3f803f80u;   // bf16 1.0 x2
        ones8 = o.v;
    }

    floatx4 O0[4], O1[4];
    #pragma unroll
    for (int g = 0; g < 4; ++g) {
        O0[g] = (floatx4){0.f,0.f,0.f,0.f};
        O1[g] = (floatx4){0.f,0.f,0.f,0.f};
    }
    floatx4 lA = (floatx4){0.f,0.f,0.f,0.f};
    floatx4 lB = (floatx4){0.f,0.f,0.f,0.f};

    // staging geometry: 128 threads, 8/row; 4 row-passes (sr+16j) per matrix
    const int sr = t >> 3, t7 = t & 7;
    const int kwb  = (sr*64 + t7*8) ^ ((sr & 7) << 3);
    // V key-chunk kc=2*t7 -> pos-chunk pc0 = 8*(kc>>3)+2*(kc&3)+((kc>>2)&1)
    const int pc0  = ((t7 >> 2) << 3) | ((t7 & 1) << 2) | ((t7 >> 1) & 1);
    const int vwb0 = (sr*64 + pc0*4)     ^ ((sr & 7) << 3);
    const int vwb1 = (sr*64 + pc0*4 + 8) ^ ((sr & 7) << 3);
    const ushort* kpt = Kb + qkbase + (size_t)sr * DK + t7*8;
    const ushort* vpt = VT + ((size_t)(h*DK + sr)) * BS + b*SEQ + t7*8;

    // fragment read offsets (tile-invariant; +g*1024 folds into ds offset imm)
    const int kro0 = (lr*64 + lq*8)      ^ ((lr & 7) << 3);
    const int kro1 = (lr*64 + 32 + lq*8) ^ ((lr & 7) << 3);

    uint4 kv0, kv1, kv2, kv3, vv0, vv1, vv2, vv3;

#define GLOAD(T)                                                              \
    {                                                                         \
        const ushort* kg = kpt + (size_t)(T) * 64 * DK;                       \
        const ushort* vg = vpt + (T) * 64;                                    \
        kv0 = *(const uint4*)(kg);                                            \
        kv1 = *(const uint4*)(kg + 16*DK);                                    \
        kv2 = *(const uint4*)(kg + 32*DK);                                    \
        kv3 = *(const uint4*)(kg + 48*DK);                                    \
        vv0 = *(const uint4*)(vg);                                            \
        vv1 = *(const uint4*)(vg + (size_t)16*BS);                            \
        vv2 = *(const uint4*)(vg + (size_t)32*BS);                            \
        vv3 = *(const uint4*)(vg + (size_t)48*BS);                            \
    }

#define STAGE()                                                               \
    {                                                                         \
        *(uint4*)&Ks[kwb]        = kv0;                                       \
        *(uint4*)&Ks[kwb + 1024] = kv1;                                       \
        *(uint4*)&Ks[kwb + 2048] = kv2;                                       \
        *(uint4*)&Ks[kwb + 3072] = kv3;                                       \
        *(uint2*)&Vs[vwb0]        = make_uint2(vv0.x, vv0.y);                 \
        *(uint2*)&Vs[vwb1]        = make_uint2(vv0.z, vv0.w);                 \
        *(uint2*)&Vs[vwb0 + 1024] = make_uint2(vv1.x, vv1.y);                 \
        *(uint2*)&Vs[vwb1 + 1024] = make_uint2(vv1.z, vv1.w);                 \
        *(uint2*)&Vs[vwb0 + 2048] = make_uint2(vv2.x, vv2.y);                 \
        *(uint2*)&Vs[vwb1 + 2048] = make_uint2(vv2.z, vv2.w);                 \
        *(uint2*)&Vs[vwb0 + 3072] = make_uint2(vv3.x, vv3.y);                 \
        *(uint2*)&Vs[vwb1 + 3072] = make_uint2(vv3.z, vv3.w);                 \
    }

#define COMPUTE(LASTT)                                                        \
    {                                                                         \
        uint2 pk0[4], pk1[4];                                                 \
        _Pragma("unroll")                                                     \
        for (int g = 0; g < 4; ++g) {                                         \
            bf16x8 kf0 = *(const bf16x8*)&Ks[kro0 + g*1024];                  \
            bf16x8 kf1 = *(const bf16x8*)&Ks[kro1 + g*1024];                  \
            floatx4 s0 = (floatx4){0.f,0.f,0.f,0.f};                          \
            s0 = __builtin_amdgcn_mfma_f32_16x16x32_bf16(kf0, qA0, s0,0,0,0); \
            s0 = __builtin_amdgcn_mfma_f32_16x16x32_bf16(kf1, qA1, s0,0,0,0); \
            floatx4 s1 = (floatx4){0.f,0.f,0.f,0.f};                          \
            s1 = __builtin_amdgcn_mfma_f32_16x16x32_bf16(kf0, qB0, s1,0,0,0); \
            s1 = __builtin_amdgcn_mfma_f32_16x16x32_bf16(kf1, qB1, s1,0,0,0); \
            float a0 = __builtin_amdgcn_exp2f(s0[0]);                         \
            float a1 = __builtin_amdgcn_exp2f(s0[1]);                         \
            float a2 = __builtin_amdgcn_exp2f(s0[2]);                         \
            float a3 = __builtin_amdgcn_exp2f(s0[3]);                         \
            float b0 = __builtin_amdgcn_exp2f(s1[0]);                         \
            float b1 = __builtin_amdgcn_exp2f(s1[1]);                         \
            float b2 = __builtin_amdgcn_exp2f(s1[2]);                         \
            float b3 = __builtin_amdgcn_exp2f(s1[3]);                         \
            if (LASTT) {                                                      \
                const int kbase = g*16 + lq*4;                                \
                a0 = (kbase + 0 <= lim0) ? a0 : 0.f;                          \
                a1 = (kbase + 1 <= lim0) ? a1 : 0.f;                          \
                a2 = (kbase + 2 <= lim0) ? a2 : 0.f;                          \
                a3 = (kbase + 3 <= lim0) ? a3 : 0.f;                          \
                b0 = (kbase + 0 <= lim1) ? b0 : 0.f;                          \
                b1 = (kbase + 1 <= lim1) ? b1 : 0.f;                          \
                b2 = (kbase + 2 <= lim1) ? b2 : 0.f;                          \
                b3 = (kbase + 3 <= lim1) ? b3 : 0.f;                          \
            }                                                                 \
            pk0[g] = make_uint2(cvtpk(a0, a1), cvtpk(a2, a3));                \
            pk1[g] = make_uint2(cvtpk(b0, b1), cvtpk(b2, b3));                \
        }                                                                     \
        __builtin_amdgcn_s_setprio(1);                                        \
        _Pragma("unroll")                                                     \
        for (int c = 0; c < 2; ++c) {                                         \
            union { uint u[4]; bf16x8 v; } a0u, a1u;                          \
            a0u.u[0] = pk0[2*c].x;   a0u.u[1] = pk0[2*c].y;                   \
            a0u.u[2] = pk0[2*c+1].x; a0u.u[3] = pk0[2*c+1].y;                 \
            a1u.u[0] = pk1[2*c].x;   a1u.u[1] = pk1[2*c].y;                   \
            a1u.u[2] = pk1[2*c+1].x; a1u.u[3] = pk1[2*c+1].y;                 \
            lA = __builtin_amdgcn_mfma_f32_16x16x32_bf16(a0u.v, ones8, lA,0,0,0); \
            lB = __builtin_amdgcn_mfma_f32_16x16x32_bf16(a1u.v, ones8, lB,0,0,0); \
            const int vro = c ? kro1 : kro0;                                  \
            _Pragma("unroll")                                                 \
            for (int g2 = 0; g2 < 4; ++g2) {                                  \
                bf16x8 vf = *(const bf16x8*)&Vs[vro + g2*1024];               \
                O0[g2] = __builtin_amdgcn_mfma_f32_16x16x32_bf16(a0u.v, vf, O0[g2],0,0,0); \
                O1[g2] = __builtin_amdgcn_mfma_f32_16x16x32_bf16(a1u.v, vf, O1[g2],0,0,0); \
            }                                                                 \
        }                                                                     \
        __builtin_amdgcn_s_setprio(0);                                        \
    }

    GLOAD(t0);
    const bool haslast = (t1 == nt);          // this chunk owns the masked tile
    const int tmain = haslast ? t1 - 1 : t1;
    {
        const int lim0 = 0, lim1 = 0;          // unused (mask folded away)
        for (int tile = t0; tile < tmain; ++tile) {
            __syncthreads();
            STAGE();
            __syncthreads();
            if (tile + 1 < t1) GLOAD(tile + 1);
            COMPUTE(false);
        }
    }
    if (haslast) {
        __syncthreads();
        STAGE();
        __syncthreads();
        const int lim0 = qw + lr - (nt - 1)*64;
        const int lim1 = lim0 + 16;
        COMPUTE(true);
    }
#undef GLOAD
#undef STAGE
#undef COMPUTE

    // lA[r] = sum_k P for q-row lq*4+r (replicated across lr); lB: rows 16-31
    if (nch == 1) {
        #pragma unroll
        for (int r = 0; r < 4; ++r) {
            float li0 = 1.f / lA[r];
            float li1 = 1.f / lB[r];
            int s0r = qw + lq*4 + r;
            int s1r = qw + 16 + lq*4 + r;
            #pragma unroll
            for (int g2 = 0; g2 < 4; ++g2) {
                attnb[((size_t)(b*SEQ + s0r))*DM + h*DK + g2*16 + lr] = f2bu(O0[g2][r] * li0);
                attnb[((size_t)(b*SEQ + s1r))*DM + h*DK + g2*16 + lr] = f2bu(O1[g2][r] * li1);
            }
        }
    } else {
        const int slot = ((b*NUM_HEADS + h)*24 + (qt - 8))*4 + chunk;
        ushort* Op = Opart + (size_t)slot * 4096;
        #pragma unroll
        for (int r = 0; r < 4; ++r) {
            int ql0 = w*32 + lq*4 + r;
            int ql1 = w*32 + 16 + lq*4 + r;
            #pragma unroll
            for (int g2 = 0; g2 < 4; ++g2) {
                Op[ql0*64 + g2*16 + lr] = f2bu(O0[g2][r]);
                Op[ql1*64 + g2*16 + lr] = f2bu(O1[g2][r]);
            }
        }
        if (lr == 0) {
            #pragma unroll
            for (int r = 0; r < 4; ++r) {
                lpart[(size_t)slot*64 + w*32 + lq*4 + r]      = lA[r];
                lpart[(size_t)slot*64 + w*32 + 16 + lq*4 + r] = lB[r];
            }
        }
    }
}

// ---------------------------------------------------------------------------
// Combine: for qt>=8, O = (sum_c O_c)/(sum_c l_c) -> attnb bf16.
// grid 768 = 32 (b,h) x 24 qt.
// ---------------------------------------------------------------------------
__global__ __launch_bounds__(256)
void combine(const ushort* __restrict__ Opart, const float* __restrict__ lpart,
             ushort* __restrict__ attnb)
{
    int gx = blockIdx.x;
    int qti = gx % 24, bh = gx / 24;
    int h = bh & 15, b = bh >> 4;
    int qt = 8 + qti;
    int nch = (qt >> 3) + 1;          // 2..4
    int tid = threadIdx.x;
    int row = tid >> 2, c0 = (tid & 3) * 16;
    const int base_slot = (bh*24 + qti)*4;

    float acc[16];
    #pragma unroll
    for (int e = 0; e < 16; ++e) acc[e] = 0.f;
    float l = 0.f;

    for (int c = 0; c < nch; ++c) {
        const ushort* Op = Opart + (size_t)(base_slot + c)*4096 + row*64 + c0;
        uint4 u0 = *(const uint4*)(Op);
        uint4 u1 = *(const uint4*)(Op + 8);
        const ushort* h0 = (const ushort*)&u0;
        const ushort* h1 = (const ushort*)&u1;
        #pragma unroll
        for (int e = 0; e < 8; ++e) { acc[e]   += bu2f(h0[e]); }
        #pragma unroll
        for (int e = 0; e < 8; ++e) { acc[8+e] += bu2f(h1[e]); }
        l += lpart[(size_t)(base_slot + c)*64 + row];
    }
    float li = 1.f / l;
    int s = qt*64 + row;
    ushort* dst = attnb + ((size_t)(b*SEQ + s))*DM + h*DK + c0;
    #pragma unroll
    for (int e = 0; e < 16; ++e) dst[e] = f2bu(acc[e] * li);
}

// ---------------------------------------------------------------------------
extern "C" void kernel_launch(void* const* d_in, const int* in_sizes, int n_in,
                              void* d_out, int out_size, void* d_ws, size_t ws_size,
                              hipStream_t stream) {
    const float* x   = (const float*)d_in[0];
    const float* Wq  = (const float*)d_in[1];
    const float* Wk  = (const float*)d_in[2];
    const float* Wv  = (const float*)d_in[3];
    const float* Wo  = (const float*)d_in[4];
    const int*   pos = (const int*)d_in[5];
    float* out = (float*)d_out;

    const size_t MB = 1u << 20;
    char* ws = (char*)d_ws;
    // xb/Wqkb/Wvb dead after projections; Opart (24 MB) aliases them.
    ushort* xb    = (ushort*)(ws);             //  8 MB  [4096,1024]
    ushort* Wqkb  = (ushort*)(ws +  8*MB);     //  4 MB  [Wq;Wk]
    ushort* Wvb   = (ushort*)(ws + 12*MB);     //  2 MB
    ushort* Opart = (ushort*)(ws);             // 24 MB  [3072 slots][64][64] bf16
    float*  lpart = (float*)(ws + 24*MB);      //  768 KB
    ushort* Qb    = (ushort*)(ws + 25*MB);     //  8 MB  [b,h,s,64] (Q scaled)
    ushort* Kb    = (ushort*)(ws + 33*MB);     //  8 MB  (== Qb + 4194304)
    ushort* VT    = (ushort*)(ws + 41*MB);     //  8 MB  [h*64+dv, b*2048+s]
    ushort* attnb = (ushort*)(ws + 49*MB);     //  8 MB  [4096,1024]
    float2* ropeT = (float2*)(ws + 57*MB);     //  0.5 MB
    ushort* Wob   = (ushort*)(ws + 58*MB);     //  2 MB  (survives to out-GEMM)

    dim3 blk(256);
    castall<<<4352, blk, 0, stream>>>(x, Wq, Wk, Wv, Wo, pos,
                                      xb, Wqkb, Wvb, Wob, ropeT);

    proj_fused<<<768, blk, 0, stream>>>(xb, Wqkb, Wvb, Qb, VT, ropeT);

    attn_mfma<<<dim3(80, NUM_HEADS, BATCHN), dim3(128), 0, stream>>>(Qb, Kb, VT, attnb,
                                                                     Opart, lpart);
    combine<<<768, blk, 0, stream>>>(Opart, lpart, attnb);

    gemm_out<<<dim3(16,32), blk, 0, stream>>>(attnb, Wob, out);
}